// Round 1
// 288.517 us; speedup vs baseline: 1.0807x; 1.0807x over previous
//
#include <hip/hip_runtime.h>
#include <hip/hip_bf16.h>

// Problem: B=4,S=4096 tokens (16384), HIDDEN=1024, 16 heads x 64 dim.
// "Attention" mixes HEADS per token (16x16 softmax over heads), not sequence.
// Inputs/output fp32; compute bf16-MFMA w/ fp32 accumulate.
//
// R5 -> R6 (R5: 311.8us; QKV gemm 130us/781TF, MfmaUtil 34% = the m97
// 2-barrier structure's ~900TF ceiling):
//   Port both GEMMs to the 256^2 / BK=64 / 8-wave 8-phase template
//   (T2 LDS XOR swizzle + T3/T4 counted vmcnt + T5 setprio):
//   - 4 quadrant-phases per K-tile (gray code over mi-half x ni-half),
//     16 MFMA + 4..12 ds_read_b128 each, 2 s_barrier per phase.
//   - interleaved half-tiles: A.h = rows {h*64..h*64+63} u {128+h*64..},
//     B.g = rows {g*32 ..} u ... so each phase reads exactly one A-half,
//     one B-half -> 1 half-tile staged per phase into the region whose
//     last reader finished the previous phase (WAR safe via end barrier).
//   - stage->read distance = 6 phases; per-phase s_waitcnt vmcnt(8)
//     (needs <=10; never drains to 0 in the main loop).
//   - chunk-XOR swizzle c^=(row&7) on 16B chunks, applied on the global
//     source (linear global_load_lds dest) and on the ds_read address:
//     frag reads are bank-uniform (8 dw/bank/wave = minimum).
// attn/cvt/fallback untouched this round.

typedef __bf16 bf16;
typedef __attribute__((ext_vector_type(8))) __bf16 bf16x8;
typedef __attribute__((ext_vector_type(4))) float floatx4;

#define HIDDEN 1024
#define BM 128
#define BN 128
#define BK 32

#define FENCE() asm volatile("" ::: "memory")
#define BAR()                                                                  \
    do {                                                                       \
        FENCE();                                                               \
        __builtin_amdgcn_s_barrier();                                          \
        FENCE();                                                               \
    } while (0)
#define VMCNT(N) asm volatile("s_waitcnt vmcnt(" #N ")" ::: "memory")

__device__ __forceinline__ void async_load16(const bf16* g, bf16* lds) {
    __builtin_amdgcn_global_load_lds(
        (const __attribute__((address_space(1))) void*)g,
        (__attribute__((address_space(3))) void*)lds, 16, 0, 0);
}

__device__ __forceinline__ bf16x8 load8(const bf16* p) {
    return *(const bf16x8*)p;
}
__device__ __forceinline__ bf16x8 load8(const float* p) {
    floatx4 lo = *(const floatx4*)p;
    floatx4 hi = *(const floatx4*)(p + 4);
    bf16x8 r;
#pragma unroll
    for (int i = 0; i < 4; ++i) { r[i] = (bf16)lo[i]; r[i + 4] = (bf16)hi[i]; }
    return r;
}

// ---------- one-time fp32 -> bf16 conversion: x then packed wq|wk|wv|wo ----
__global__ __launch_bounds__(256) void cvt_all(
    const float* __restrict__ x,
    const float* __restrict__ wq, const float* __restrict__ wk,
    const float* __restrict__ wv, const float* __restrict__ wo,
    bf16* __restrict__ xb, bf16* __restrict__ wpk, int mh8)
{
    const int per = (HIDDEN * HIDDEN) / 8;   // 131072 chunks per weight
    int i = blockIdx.x * 256 + threadIdx.x;
    if (i < mh8) {
        *(bf16x8*)&xb[(size_t)i * 8] = load8(&x[(size_t)i * 8]);
    } else {
        int j = i - mh8;
        int wsel = j / per;
        int off  = (j - wsel * per) * 8;
        const float* s = wsel == 0 ? wq : wsel == 1 ? wk : wsel == 2 ? wv : wo;
        *(bf16x8*)&wpk[(size_t)j * 8] = load8(&s[off]);
    }
}

// ---------- 256^2 8-phase GEMM ------------------------------------------
// C[m,n] = sum_k A[m,k]*W[n,k]. 512 thr = 8 waves (2M x 4N), wave tile
// 128x64, acc[8][4] 16x16 frags. LDS 128KB: [dbuf2][half2][128x64] x {A,B}.

// stage one 16KB half-tile (2 x global_load_lds/thread, linear LDS dest,
// inverse-swizzled global source). S=64 for A-halves, S=32 for B-halves.
template <int S>
__device__ __forceinline__ void stage_half(const bf16* __restrict__ gbase,
                                           int ld, int kt, bf16* lhalf,
                                           int h, int tid) {
#pragma unroll
    for (int j = 0; j < 2; ++j) {
        const int ci = j * 512 + tid;
        const int rr = ci >> 3;
        const int cs = (ci & 7) ^ (rr & 7);
        const int gr = h * S + (rr & (S - 1)) + (rr >> (S == 64 ? 6 : 5)) * (2 * S);
        async_load16(&gbase[(size_t)gr * ld + kt + cs * 8], &lhalf[ci * 8]);
    }
}

// frag reads from a half (both k-chunks), swizzled: chunk=(kk*4+quad)^(col&7)
__device__ __forceinline__ void ld_a4(const bf16* h, int wm, int col, int quad,
                                      int cx, bf16x8* a) {
#pragma unroll
    for (int i = 0; i < 4; ++i) {
        const int rr = i * 16 + col + (wm << 6);
#pragma unroll
        for (int kk = 0; kk < 2; ++kk)
            a[i * 2 + kk] =
                *(const bf16x8*)&h[rr * 64 + (((kk << 2) + quad) ^ cx) * 8];
    }
}
__device__ __forceinline__ void ld_b2(const bf16* h, int wn, int col, int quad,
                                      int cx, bf16x8* b) {
#pragma unroll
    for (int j = 0; j < 2; ++j) {
        const int rr = j * 16 + col + (wn << 5);
#pragma unroll
        for (int kk = 0; kk < 2; ++kk)
            b[j * 2 + kk] =
                *(const bf16x8*)&h[rr * 64 + (((kk << 2) + quad) ^ cx) * 8];
    }
}

template <int H, int G>
__device__ __forceinline__ void mmq(floatx4 (&acc)[8][4], const bf16x8 (&a)[8],
                                    const bf16x8 (&bb)[4]) {
    __builtin_amdgcn_s_setprio(1);
#pragma unroll
    for (int i = 0; i < 4; ++i)
#pragma unroll
        for (int j = 0; j < 2; ++j)
#pragma unroll
            for (int kk = 0; kk < 2; ++kk)
                acc[H * 4 + i][G * 2 + j] =
                    __builtin_amdgcn_mfma_f32_16x16x32_bf16(
                        a[i * 2 + kk], bb[j * 2 + kk],
                        acc[H * 4 + i][G * 2 + j], 0, 0, 0);
    __builtin_amdgcn_s_setprio(0);
}

template <typename TC>
__global__ __launch_bounds__(512, 2) void gemm8p(
    const bf16* __restrict__ A, const bf16* __restrict__ W,
    TC* __restrict__ C, int K, int lda, int ldc)
{
    __shared__ __align__(16) bf16 sA[2][2][128 * 64];   // 64 KB
    __shared__ __align__(16) bf16 sB[2][2][128 * 64];   // 64 KB

    const int tid  = threadIdx.x;
    const int lane = tid & 63;
    const int w    = tid >> 6;       // 0..7
    const int wm   = w >> 2;         // 0..1
    const int wn   = w & 3;          // 0..3
    const int m0   = blockIdx.x * 256;
    const int n0   = blockIdx.y * 256;
    const int col  = lane & 15;
    const int quad = lane >> 4;
    const int cx   = col & 7;

    const bf16* Ab = A + (size_t)m0 * lda;
    const bf16* Wb = W + (size_t)n0 * K;

    floatx4 acc[8][4] = {};
    bf16x8 a[8], b0[4], b1[4];

    const int T = K / 64;

    // Prologue: tile0 fully (A.h0,B.h0,B.h1,A.h1) + tile1 (A.h0,B.h0,B.h1).
    // A.h1(1) is staged at P0(0) per the steady-state schedule.
    stage_half<64>(Ab, lda, 0, sA[0][0], 0, tid);
    stage_half<32>(Wb, K,   0, sB[0][0], 0, tid);
    stage_half<32>(Wb, K,   0, sB[0][1], 1, tid);
    stage_half<64>(Ab, lda, 0, sA[0][1], 1, tid);
    if (T > 1) {
        stage_half<64>(Ab, lda, 64, sA[1][0], 0, tid);
        stage_half<32>(Wb, K,   64, sB[1][0], 0, tid);
        stage_half<32>(Wb, K,   64, sB[1][1], 1, tid);
        VMCNT(6);                    // 14 issued -> 8 done = tile0 complete
    } else {
        VMCNT(0);
    }
    BAR();

    for (int t = 0; t < T; ++t) {
        const int b   = t & 1;
        const int kt1 = (t + 1) * 64;
        const int kt2 = (t + 2) * 64;

        // P0: quad(0,0). reads A.h0(t), B.h0(t); stages A.h1(t+1).
        ld_a4(sA[b][0], wm, col, quad, cx, a);
        ld_b2(sB[b][0], wn, col, quad, cx, b0);
        if (t + 1 < T) stage_half<64>(Ab, lda, kt1, sA[b ^ 1][1], 1, tid);
        VMCNT(8);
        BAR();
        mmq<0, 0>(acc, a, b0);
        BAR();

        // P1: quad(0,1). reads B.h1(t); stages A.h0(t+2) over A.h0(t).
        ld_b2(sB[b][1], wn, col, quad, cx, b1);
        if (t + 2 < T) stage_half<64>(Ab, lda, kt2, sA[b][0], 0, tid);
        VMCNT(8);
        BAR();
        mmq<0, 1>(acc, a, b1);
        BAR();

        // P2: quad(1,1). reads A.h1(t); stages B.h0(t+2) over B.h0(t).
        ld_a4(sA[b][1], wm, col, quad, cx, a);
        if (t + 2 < T) stage_half<32>(Wb, K, kt2, sB[b][0], 0, tid);
        VMCNT(8);
        BAR();
        mmq<1, 1>(acc, a, b1);
        BAR();

        // P3: quad(1,0). no reads (b0 kept in regs); stages B.h1(t+2).
        if (t + 2 < T) stage_half<32>(Wb, K, kt2, sB[b][1], 1, tid);
        VMCNT(8);
        BAR();
        mmq<1, 0>(acc, a, b0);
        BAR();
    }

#pragma unroll
    for (int mi = 0; mi < 8; ++mi) {
#pragma unroll
        for (int r = 0; r < 4; ++r) {
            const int row = m0 + wm * 128 + mi * 16 + quad * 4 + r;
#pragma unroll
            for (int ni = 0; ni < 4; ++ni) {
                const int cc = n0 + wn * 64 + ni * 16 + col;
                C[(size_t)row * ldc + cc] = (TC)acc[mi][ni][r];
            }
        }
    }
}

// ---------- R3 fallback GEMM (fp32-or-bf16 in, register staging) ----------
template <typename TA, typename TB, typename TC>
__global__ __launch_bounds__(256, 2) void gemm_bt(
    const TA* __restrict__ A, const TB* __restrict__ W,
    TC* __restrict__ C, int M, int N, int K)
{
    __shared__ __align__(16) bf16 sA[BM * BK];
    __shared__ __align__(16) bf16 sB[BN * BK];

    const int tid  = threadIdx.x;
    const int lane = tid & 63;
    const int w    = tid >> 6;
    const int wm   = w >> 1;
    const int wn   = w & 1;
    const int m0   = blockIdx.x * BM;
    const int n0   = blockIdx.y * BN;
    const int col  = lane & 15;
    const int quad = lane >> 4;

    floatx4 acc[4][4] = {};

    for (int kt = 0; kt < K; kt += BK) {
        bf16x8 ga[2], gb[2];
#pragma unroll
        for (int i = 0; i < 2; ++i) {
            const int c   = i * 256 + tid;
            const int row = c >> 2;
            const int kc  = c & 3;
            ga[i] = load8(&A[(size_t)(m0 + row) * K + kt + kc * 8]);
            gb[i] = load8(&W[(size_t)(n0 + row) * K + kt + kc * 8]);
        }
        __syncthreads();
#pragma unroll
        for (int i = 0; i < 2; ++i) {
            const int c = i * 256 + tid;
            *(bf16x8*)&sA[c * 8] = ga[i];
            *(bf16x8*)&sB[c * 8] = gb[i];
        }
        __syncthreads();

        bf16x8 af[4], bfr[4];
#pragma unroll
        for (int mi = 0; mi < 4; ++mi)
            af[mi] = *(const bf16x8*)&sA[(wm * 64 + mi * 16 + col) * BK + quad * 8];
#pragma unroll
        for (int ni = 0; ni < 4; ++ni)
            bfr[ni] = *(const bf16x8*)&sB[(wn * 64 + ni * 16 + col) * BK + quad * 8];

#pragma unroll
        for (int mi = 0; mi < 4; ++mi)
#pragma unroll
            for (int ni = 0; ni < 4; ++ni)
                acc[mi][ni] = __builtin_amdgcn_mfma_f32_16x16x32_bf16(
                    af[mi], bfr[ni], acc[mi][ni], 0, 0, 0);
    }

#pragma unroll
    for (int mi = 0; mi < 4; ++mi) {
#pragma unroll
        for (int r = 0; r < 4; ++r) {
            const int row = m0 + wm * 64 + mi * 16 + quad * 4 + r;
#pragma unroll
            for (int ni = 0; ni < 4; ++ni) {
                const int cc = n0 + wn * 64 + ni * 16 + col;
                C[(size_t)row * N + cc] = (TC)acc[mi][ni][r];
            }
        }
    }
}

// ---------- per-token head-mixing attention ----------
__global__ __launch_bounds__(256) void attn_heads(
    bf16* base, size_t koff, size_t voff, int stride, bf16* ob)
{
    __shared__ __align__(16) bf16 sP[4][16 * 40];    // [wave][h][g pad->32, row 40]
    __shared__ __align__(16) bf16 sVt[4][64 * 40];   // [wave][d][g pad->32, row 40]

    const int tid   = threadIdx.x;
    const int lane  = tid & 63;
    const int w     = tid >> 6;
    const int token = blockIdx.x * 4 + w;
    const int col   = lane & 15;
    const int quad  = lane >> 4;

    bf16* qt = base + (size_t)token * stride;
    const bf16* kt = qt + koff;
    const bf16* vt = qt + voff;
    bf16* ot = ob + (size_t)token * HIDDEN;

    const bf16x8 z = {};
    *(bf16x8*)&sVt[w][lane * 40 + 16] = z;
    *(bf16x8*)&sVt[w][lane * 40 + 24] = z;
    if (lane < 16) {
        *(bf16x8*)&sP[w][lane * 40 + 16] = z;
        *(bf16x8*)&sP[w][lane * 40 + 24] = z;
    }

    bf16x8 qa0 = *(const bf16x8*)&qt[col * 64 + quad * 8];
    bf16x8 qa1 = *(const bf16x8*)&qt[col * 64 + 32 + quad * 8];
    bf16x8 kb0 = *(const bf16x8*)&kt[col * 64 + quad * 8];
    bf16x8 kb1 = *(const bf16x8*)&kt[col * 64 + 32 + quad * 8];
    floatx4 s = {};
    s = __builtin_amdgcn_mfma_f32_16x16x32_bf16(qa0, kb0, s, 0, 0, 0);
    s = __builtin_amdgcn_mfma_f32_16x16x32_bf16(qa1, kb1, s, 0, 0, 0);

    bf16x8 vc0, vc1;
#pragma unroll
    for (int j = 0; j < 8; ++j)  vc0[j] = vt[j * 64 + lane];
#pragma unroll
    for (int j = 0; j < 8; ++j)  vc1[j] = vt[(j + 8) * 64 + lane];
    *(bf16x8*)&sVt[w][lane * 40]     = vc0;
    *(bf16x8*)&sVt[w][lane * 40 + 8] = vc1;

#pragma unroll
    for (int r = 0; r < 4; ++r) {
        float x = s[r] * 0.125f;
        float m = x;
#pragma unroll
        for (int off = 1; off < 16; off <<= 1)
            m = fmaxf(m, __shfl_xor(m, off));
        float e = __expf(x - m);
        float su = e;
#pragma unroll
        for (int off = 1; off < 16; off <<= 1)
            su += __shfl_xor(su, off);
        sP[w][(quad * 4 + r) * 40 + col] = (bf16)(e / su);
    }

    bf16x8 pa = *(const bf16x8*)&sP[w][col * 40 + quad * 8];
#pragma unroll
    for (int dt = 0; dt < 4; ++dt) {
        bf16x8 vb = *(const bf16x8*)&sVt[w][(dt * 16 + col) * 40 + quad * 8];
        floatx4 o4 = {};
        o4 = __builtin_amdgcn_mfma_f32_16x16x32_bf16(pa, vb, o4, 0, 0, 0);
#pragma unroll
        for (int r = 0; r < 4; ++r)
            ot[(quad * 4 + r) * 64 + dt * 16 + col] = (bf16)o4[r];
    }
}

extern "C" void kernel_launch(void* const* d_in, const int* in_sizes, int n_in,
                              void* d_out, int out_size, void* d_ws, size_t ws_size,
                              hipStream_t stream) {
    const float* x  = (const float*)d_in[0];
    const float* wq = (const float*)d_in[1];
    const float* wk = (const float*)d_in[2];
    const float* wv = (const float*)d_in[3];
    const float* wo = (const float*)d_in[4];
    float* out = (float*)d_out;

    const int M = in_sizes[0] / HIDDEN;   // 16384 tokens
    const size_t MH = (size_t)M * HIDDEN;
    const size_t WH = (size_t)HIDDEN * HIDDEN;

    const size_t need = (MH + 4 * WH + (size_t)M * 3 * HIDDEN) * sizeof(bf16);

    if (ws_size >= need && (M % 256) == 0) {
        // Fast path: convert once, 8-phase bf16 GEMMs.
        bf16* xb  = (bf16*)d_ws;          // [M][1024]; reused as O after QKV
        bf16* wpk = xb + MH;              // [4][1024][1024] packed q|k|v|o
        bf16* qkv = wpk + 4 * WH;         // [M][3072]

        const int mh8 = (int)(MH / 8);
        const int nchunks = mh8 + (int)(4 * WH / 8);
        cvt_all<<<dim3(nchunks / 256), 256, 0, stream>>>(x, wq, wk, wv, wo,
                                                         xb, wpk, mh8);

        gemm8p<bf16><<<dim3(M / 256, 3 * HIDDEN / 256), 512, 0, stream>>>(
            xb, wpk, qkv, HIDDEN, HIDDEN, 3 * HIDDEN);

        // xb is dead now; attn writes O into it (dense lda=1024 for Wo GEMM).
        attn_heads<<<dim3(M / 4), 256, 0, stream>>>(qkv, 1024, 2048,
                                                    3 * HIDDEN, xb);

        gemm8p<float><<<dim3(M / 256, HIDDEN / 256), 512, 0, stream>>>(
            xb, wpk + 3 * WH, out, HIDDEN, HIDDEN, HIDDEN);
    } else {
        // R3 proven fallback (needs 100.7 MB).
        bf16* qb = (bf16*)d_ws;
        bf16* kb = qb + MH;
        bf16* vb = kb + MH;
        dim3 grid(M / BM, HIDDEN / BN), block(256);
        gemm_bt<float, float, bf16><<<grid, block, 0, stream>>>(x, wq, qb, M, HIDDEN, HIDDEN);
        gemm_bt<float, float, bf16><<<grid, block, 0, stream>>>(x, wk, kb, M, HIDDEN, HIDDEN);
        gemm_bt<float, float, bf16><<<grid, block, 0, stream>>>(x, wv, vb, M, HIDDEN, HIDDEN);
        attn_heads<<<dim3(M / 4), block, 0, stream>>>(qb, MH, 2 * MH, HIDDEN, qb);
        gemm_bt<bf16, float, float><<<grid, block, 0, stream>>>(qb, wo, out, M, HIDDEN, HIDDEN);
    }
}